// Round 1
// baseline (9186.736 us; speedup 1.0000x reference)
//
#include <hip/hip_runtime.h>
#include <math.h>

constexpr int B  = 2;
constexpr int S  = 2048;
constexpr int D  = 1024;
constexpr int H  = 16;
constexpr int DK = 64;   // == DV
constexpr float SCALE = 0.125f;  // 1/sqrt(64)

// ---------------------------------------------------------------------------
// C = A @ W^T + bias.  A: [M,K] row-major, W: [N,K] row-major, bias: [N].
// MODE 0: C row-major [M,N].
// MODE 1: scatter to head-major [B,H,S,DK]:  m = b*S+s, n = h*DK+d.
// Block: 256 threads, 64x64 tile, K-panel 16, 4x4 accumulators per thread.
// ---------------------------------------------------------------------------
template<int MODE>
__global__ __launch_bounds__(256)
void gemm_bt(const float* __restrict__ A, const float* __restrict__ W,
             const float* __restrict__ bias, float* __restrict__ C,
             int M, int N, int K)
{
    __shared__ float As[16][65];   // [k][m], +1 pad
    __shared__ float Ws[16][65];   // [k][n]

    const int tid = threadIdx.x;
    const int tx  = tid & 15;      // n-group
    const int ty  = tid >> 4;      // m-group
    const int m0  = blockIdx.y * 64;
    const int n0  = blockIdx.x * 64;

    const int lr = tid >> 2;         // 0..63 : tile row loaded by this thread
    const int lk = (tid & 3) * 4;    // 0,4,8,12 : k offset (float4)

    float c[4][4] = {};

    for (int k0 = 0; k0 < K; k0 += 16) {
        float4 av = *(const float4*)(A + (size_t)(m0 + lr) * K + k0 + lk);
        float4 wv = *(const float4*)(W + (size_t)(n0 + lr) * K + k0 + lk);
        __syncthreads();   // previous panel fully consumed
        As[lk+0][lr] = av.x; As[lk+1][lr] = av.y;
        As[lk+2][lr] = av.z; As[lk+3][lr] = av.w;
        Ws[lk+0][lr] = wv.x; Ws[lk+1][lr] = wv.y;
        Ws[lk+2][lr] = wv.z; Ws[lk+3][lr] = wv.w;
        __syncthreads();

        #pragma unroll
        for (int kk = 0; kk < 16; ++kk) {
            float a[4], b[4];
            #pragma unroll
            for (int i = 0; i < 4; ++i) a[i] = As[kk][ty*4+i];
            #pragma unroll
            for (int j = 0; j < 4; ++j) b[j] = Ws[kk][tx*4+j];
            #pragma unroll
            for (int i = 0; i < 4; ++i)
                #pragma unroll
                for (int j = 0; j < 4; ++j)
                    c[i][j] += a[i] * b[j];
        }
    }

    #pragma unroll
    for (int i = 0; i < 4; ++i) {
        const int m = m0 + ty*4 + i;
        #pragma unroll
        for (int j = 0; j < 4; ++j) {
            const int n = n0 + tx*4 + j;
            const float val = c[i][j] + bias[n];
            if (MODE == 0) {
                C[(size_t)m * N + n] = val;
            } else {
                const int b = m >> 11;          // m / S
                const int s = m & (S - 1);
                const int h = n >> 6;           // n / DK
                const int d = n & (DK - 1);
                C[(((size_t)(b*H + h) * S + s) * DK) + d] = val;
            }
        }
    }
}

// ---------------------------------------------------------------------------
// One block per (b,h,s) query row.  Scores row (2048 floats) lives in LDS.
// ---------------------------------------------------------------------------
__global__ __launch_bounds__(256)
void attn_kernel(const float* __restrict__ Qh, const float* __restrict__ Kh,
                 const float* __restrict__ Vh, const float* __restrict__ prev,
                 const int*  __restrict__ mask, float* __restrict__ out)
{
    __shared__ float qrow[64];
    __shared__ float sc[S];
    __shared__ float red[8];
    __shared__ float red2[256];

    const int blk = blockIdx.x;            // ((b*H + h)*S + s)
    const int tid = threadIdx.x;
    const int s   = blk & (S - 1);
    const int bh  = blk >> 11;             // b*H + h
    const int b   = blk >> 15;             // / (H*S)
    const int h   = bh & (H - 1);
    const size_t bhBase = (size_t)bh * S;

    if (tid < 64) qrow[tid] = Qh[(size_t)blk * 64 + tid];
    __syncthreads();

    // ---- scores = q . k * SCALE + prev, masked ----
    float lmax = -INFINITY;
    const float4* qp = (const float4*)qrow;
    for (int t = tid; t < S; t += 256) {
        const float4* kp = (const float4*)(Kh + (bhBase + t) * 64);
        float acc = 0.f;
        #pragma unroll
        for (int j = 0; j < 16; ++j) {
            float4 kv = kp[j];
            float4 qv = qp[j];
            acc += qv.x*kv.x + qv.y*kv.y + qv.z*kv.z + qv.w*kv.w;
        }
        float sv = acc * SCALE + prev[(size_t)blk * S + t];
        if (mask[b*S + t] != 0) sv = -1e30f;
        sc[t] = sv;
        lmax = fmaxf(lmax, sv);
    }

    // ---- block max ----
    #pragma unroll
    for (int o = 32; o > 0; o >>= 1) lmax = fmaxf(lmax, __shfl_down(lmax, o, 64));
    if ((tid & 63) == 0) red[tid >> 6] = lmax;
    __syncthreads();
    const float mx = fmaxf(fmaxf(red[0], red[1]), fmaxf(red[2], red[3]));

    // ---- exp + block sum ----
    float lsum = 0.f;
    for (int t = tid; t < S; t += 256) {
        float e = __expf(sc[t] - mx);
        sc[t] = e;
        lsum += e;
    }
    #pragma unroll
    for (int o = 32; o > 0; o >>= 1) lsum += __shfl_down(lsum, o, 64);
    if ((tid & 63) == 0) red[4 + (tid >> 6)] = lsum;
    __syncthreads();   // also publishes all sc[] writes for the PV phase
    const float inv = 1.f / (red[4] + red[5] + red[6] + red[7]);

    // ---- PV: out[d] = sum_t w[t] * V[t,d] ----
    const int d     = tid & 63;
    const int chunk = tid >> 6;       // 0..3
    float acc = 0.f;
    const int t0 = chunk * (S/4);
    for (int t = t0; t < t0 + S/4; ++t)
        acc += sc[t] * Vh[(bhBase + t) * 64 + d];
    red2[tid] = acc;
    __syncthreads();
    if (tid < 64) {
        const float tot = red2[tid] + red2[tid+64] + red2[tid+128] + red2[tid+192];
        out[((size_t)(b*S + s)) * D + h*64 + tid] = tot * inv;
    }
}

// ---------------------------------------------------------------------------
extern "C" void kernel_launch(void* const* d_in, const int* in_sizes, int n_in,
                              void* d_out, int out_size, void* d_ws, size_t ws_size,
                              hipStream_t stream)
{
    const float* q    = (const float*)d_in[0];
    const float* k    = (const float*)d_in[1];
    const float* v    = (const float*)d_in[2];
    const float* prev = (const float*)d_in[3];
    const int*   mask = (const int*)  d_in[4];
    const float* Wq   = (const float*)d_in[5];
    const float* bq   = (const float*)d_in[6];
    const float* Wk   = (const float*)d_in[7];
    const float* bk   = (const float*)d_in[8];
    const float* Wv   = (const float*)d_in[9];
    const float* bv   = (const float*)d_in[10];
    const float* Wo   = (const float*)d_in[11];
    const float* bo   = (const float*)d_in[12];
    float* out = (float*)d_out;

    const size_t perBuf = (size_t)B * H * S * DK;   // 4 M floats = 16 MB
    float* Qh = (float*)d_ws;
    float* Kh = Qh + perBuf;
    float* Vh = Kh + perBuf;
    float* Ao = Vh + perBuf;                        // [B,S,H*DV] row-major

    dim3 bb(256);
    dim3 gg(D/64, (B*S)/64);     // N=1024, M=4096

    gemm_bt<1><<<gg, bb, 0, stream>>>(q, Wq, bq, Qh, B*S, H*DK, D);
    gemm_bt<1><<<gg, bb, 0, stream>>>(k, Wk, bk, Kh, B*S, H*DK, D);
    gemm_bt<1><<<gg, bb, 0, stream>>>(v, Wv, bv, Vh, B*S, H*DK, D);

    attn_kernel<<<dim3(B*H*S), bb, 0, stream>>>(Qh, Kh, Vh, prev, mask, Ao);

    gemm_bt<0><<<gg, bb, 0, stream>>>(Ao, Wo, bo, out, B*S, D, H*DK);
}

// Round 2
// 1597.195 us; speedup vs baseline: 5.7518x; 5.7518x over previous
//
#include <hip/hip_runtime.h>
#include <hip/hip_bf16.h>
#include <math.h>

constexpr int B  = 2;
constexpr int S  = 2048;
constexpr int D  = 1024;
constexpr int H  = 16;
constexpr int DK = 64;   // == DV
constexpr float SCALE = 0.125f;  // 1/sqrt(64), exact power of two

typedef __attribute__((ext_vector_type(8))) short bf16x8;   // 8 bf16 = 4 VGPRs
typedef __attribute__((ext_vector_type(4))) float f32x4;

__device__ inline short f2bf(float x) {
    __hip_bfloat16 h = __float2bfloat16(x);
    return *reinterpret_cast<short*>(&h);
}

// ---------------------------------------------------------------------------
// C = A @ W^T + bias.  A: [M,K] row-major, W: [N,K] row-major, bias: [N].
// MODE 0: f32 row-major [M,N].
// MODE 1: bf16 scatter to head-major [B,H,S,64], value*scale (Q: scale=0.125).
// MODE 2: bf16 scatter TRANSPOSED [B,H,64,S]  (for V).
// ---------------------------------------------------------------------------
template<int MODE>
__global__ __launch_bounds__(256)
void gemm_bt(const float* __restrict__ A, const float* __restrict__ W,
             const float* __restrict__ bias, void* __restrict__ Cout,
             int M, int N, int K, float scale)
{
    __shared__ float As[16][65];
    __shared__ float Ws[16][65];

    const int tid = threadIdx.x;
    const int tx  = tid & 15;
    const int ty  = tid >> 4;
    const int m0  = blockIdx.y * 64;
    const int n0  = blockIdx.x * 64;

    const int lr = tid >> 2;
    const int lk = (tid & 3) * 4;

    float c[4][4] = {};

    for (int k0 = 0; k0 < K; k0 += 16) {
        float4 av = *(const float4*)(A + (size_t)(m0 + lr) * K + k0 + lk);
        float4 wv = *(const float4*)(W + (size_t)(n0 + lr) * K + k0 + lk);
        __syncthreads();
        As[lk+0][lr] = av.x; As[lk+1][lr] = av.y;
        As[lk+2][lr] = av.z; As[lk+3][lr] = av.w;
        Ws[lk+0][lr] = wv.x; Ws[lk+1][lr] = wv.y;
        Ws[lk+2][lr] = wv.z; Ws[lk+3][lr] = wv.w;
        __syncthreads();

        #pragma unroll
        for (int kk = 0; kk < 16; ++kk) {
            float a[4], b[4];
            #pragma unroll
            for (int i = 0; i < 4; ++i) a[i] = As[kk][ty*4+i];
            #pragma unroll
            for (int j = 0; j < 4; ++j) b[j] = Ws[kk][tx*4+j];
            #pragma unroll
            for (int i = 0; i < 4; ++i)
                #pragma unroll
                for (int j = 0; j < 4; ++j)
                    c[i][j] += a[i] * b[j];
        }
    }

    #pragma unroll
    for (int i = 0; i < 4; ++i) {
        const int m = m0 + ty*4 + i;
        #pragma unroll
        for (int j = 0; j < 4; ++j) {
            const int n = n0 + tx*4 + j;
            const float val = c[i][j] + bias[n];
            if (MODE == 0) {
                ((float*)Cout)[(size_t)m * N + n] = val;
            } else {
                const int b = m >> 11;          // m / S
                const int s = m & (S - 1);
                const int h = n >> 6;           // n / 64
                const int d = n & 63;
                const short bv = f2bf(val * scale);
                if (MODE == 1)
                    ((short*)Cout)[(((size_t)(b*H + h) * S + s) << 6) + d] = bv;
                else // MODE 2: [B,H,64,S]
                    ((short*)Cout)[(((size_t)(b*H + h) * 64 + d) * S) + s] = bv;
            }
        }
    }
}

// ---------------------------------------------------------------------------
// Flash-style MFMA attention.
// Block = one (b,h) x 64-query tile; 4 waves x 16 q-rows each.
// Qb: [B,H,S,64] bf16 (pre-scaled by 0.125), Kb: [B,H,S,64] bf16,
// Vt: [B,H,64,S] bf16, prev: [B,H,S,S] f32, mask: [B,S] int,
// Ao: [B,S,H*64] f32.
// MFMA 16x16x32 frag maps: A/B: (m|n)=lane&15, k=quad*8+j ;
//                          C/D: col=lane&15, row=quad*4+reg.
// ---------------------------------------------------------------------------
__global__ __launch_bounds__(256)
void attn_mfma(const short* __restrict__ Qb, const short* __restrict__ Kb,
               const short* __restrict__ Vt, const float* __restrict__ prev,
               const int*  __restrict__ mask, float* __restrict__ Ao)
{
    __shared__ short Pt[4][16][72];   // per-wave P tile, +8 pad

    const int tid  = threadIdx.x;
    const int wave = tid >> 6;
    const int lane = tid & 63;
    const int l15  = lane & 15;
    const int quad = lane >> 4;

    const int bh = blockIdx.x >> 5;       // 32 q-tiles per (b,h)
    const int qt = blockIdx.x & 31;
    const int b  = bh >> 4;
    const int h  = bh & 15;
    const int q0 = qt * 64 + wave * 16;   // first q-row of this wave

    const size_t bhS = (size_t)bh * S;

    // Q A-frags (once per block): row m = lane&15, k = quad*8+j (+32)
    bf16x8 qf0, qf1;
    {
        const short* qrow = Qb + ((bhS + q0 + l15) << 6) + quad * 8;
        qf0 = *(const bf16x8*)(qrow);
        qf1 = *(const bf16x8*)(qrow + 32);
    }

    f32x4 o[4] = {};            // O accum, C-layout, 4 nv-blocks
    float m_i[4], l_i[4];
    #pragma unroll
    for (int r = 0; r < 4; ++r) { m_i[r] = -INFINITY; l_i[r] = 0.f; }

    for (int t0 = 0; t0 < S; t0 += 64) {
        // ---- QK^T ----
        f32x4 sfr[4] = {};
        #pragma unroll
        for (int nb = 0; nb < 4; ++nb) {
            const short* krow = Kb + ((bhS + t0 + nb*16 + l15) << 6) + quad * 8;
            bf16x8 kf0 = *(const bf16x8*)(krow);
            bf16x8 kf1 = *(const bf16x8*)(krow + 32);
            sfr[nb] = __builtin_amdgcn_mfma_f32_16x16x32_bf16(qf0, kf0, sfr[nb], 0, 0, 0);
            sfr[nb] = __builtin_amdgcn_mfma_f32_16x16x32_bf16(qf1, kf1, sfr[nb], 0, 0, 0);
        }

        // ---- + prev, mask, tile row-max ----
        float tmax[4];
        #pragma unroll
        for (int r = 0; r < 4; ++r) tmax[r] = -INFINITY;
        #pragma unroll
        for (int nb = 0; nb < 4; ++nb) {
            const int t = t0 + nb*16 + l15;
            const int msk = mask[b*S + t];
            #pragma unroll
            for (int r = 0; r < 4; ++r) {
                const int srow = q0 + quad*4 + r;
                float sv = sfr[nb][r] + prev[(bhS + srow) * S + t];
                if (msk) sv = -1e30f;
                sfr[nb][r] = sv;
                tmax[r] = fmaxf(tmax[r], sv);
            }
        }
        #pragma unroll
        for (int r = 0; r < 4; ++r) {
            float v = tmax[r];
            v = fmaxf(v, __shfl_xor(v, 1, 64));
            v = fmaxf(v, __shfl_xor(v, 2, 64));
            v = fmaxf(v, __shfl_xor(v, 4, 64));
            v = fmaxf(v, __shfl_xor(v, 8, 64));
            tmax[r] = v;
        }

        // ---- online-softmax update ----
        float alpha[4], lsum[4];
        #pragma unroll
        for (int r = 0; r < 4; ++r) {
            float mnew = fmaxf(m_i[r], tmax[r]);
            alpha[r] = __expf(m_i[r] - mnew);
            m_i[r] = mnew;
            lsum[r] = 0.f;
        }
        #pragma unroll
        for (int nb = 0; nb < 4; ++nb) {
            #pragma unroll
            for (int r = 0; r < 4; ++r) {
                float e = __expf(sfr[nb][r] - m_i[r]);
                lsum[r] += e;
                Pt[wave][quad*4 + r][nb*16 + l15] = f2bf(e);
            }
        }
        #pragma unroll
        for (int r = 0; r < 4; ++r) {
            float v = lsum[r];
            v += __shfl_xor(v, 1, 64);
            v += __shfl_xor(v, 2, 64);
            v += __shfl_xor(v, 4, 64);
            v += __shfl_xor(v, 8, 64);
            l_i[r] = l_i[r] * alpha[r] + v;
        }
        #pragma unroll
        for (int nv = 0; nv < 4; ++nv)
            #pragma unroll
            for (int r = 0; r < 4; ++r) o[nv][r] *= alpha[r];

        // wave-private LDS write -> read: only need LDS drain, no barrier
        __asm__ __volatile__("s_waitcnt lgkmcnt(0)" ::: "memory");

        // ---- PV ----
        bf16x8 pf0 = *(const bf16x8*)&Pt[wave][l15][quad * 8];
        bf16x8 pf1 = *(const bf16x8*)&Pt[wave][l15][32 + quad * 8];
        #pragma unroll
        for (int nv = 0; nv < 4; ++nv) {
            const short* vrow = Vt + ((size_t)bh * 64 + nv*16 + l15) * S + t0 + quad * 8;
            bf16x8 vf0 = *(const bf16x8*)(vrow);
            bf16x8 vf1 = *(const bf16x8*)(vrow + 32);
            o[nv] = __builtin_amdgcn_mfma_f32_16x16x32_bf16(pf0, vf0, o[nv], 0, 0, 0);
            o[nv] = __builtin_amdgcn_mfma_f32_16x16x32_bf16(pf1, vf1, o[nv], 0, 0, 0);
        }
    }

    // ---- epilogue: /l, store Ao[b, s, h*64+d] ----
    #pragma unroll
    for (int r = 0; r < 4; ++r) {
        const int srow = q0 + quad*4 + r;
        const float invl = 1.f / l_i[r];
        #pragma unroll
        for (int nv = 0; nv < 4; ++nv)
            Ao[((size_t)(b*S + srow)) * D + h*64 + nv*16 + l15] = o[nv][r] * invl;
    }
}

// ---------------------------------------------------------------------------
extern "C" void kernel_launch(void* const* d_in, const int* in_sizes, int n_in,
                              void* d_out, int out_size, void* d_ws, size_t ws_size,
                              hipStream_t stream)
{
    const float* q    = (const float*)d_in[0];
    const float* k    = (const float*)d_in[1];
    const float* v    = (const float*)d_in[2];
    const float* prev = (const float*)d_in[3];
    const int*   mask = (const int*)  d_in[4];
    const float* Wq   = (const float*)d_in[5];
    const float* bq   = (const float*)d_in[6];
    const float* Wk   = (const float*)d_in[7];
    const float* bk   = (const float*)d_in[8];
    const float* Wv   = (const float*)d_in[9];
    const float* bv   = (const float*)d_in[10];
    const float* Wo   = (const float*)d_in[11];
    const float* bo   = (const float*)d_in[12];
    float* out = (float*)d_out;

    const size_t perBuf = (size_t)B * H * S * 64;   // 4M elements
    short* Qb = (short*)d_ws;                       // 8 MB bf16
    short* Kb = Qb + perBuf;                        // 8 MB
    short* Vt = Kb + perBuf;                        // 8 MB, transposed [B,H,64,S]
    float* Ao = (float*)(Vt + perBuf);              // 16 MB f32

    dim3 bb(256);
    dim3 gg(D/64, (B*S)/64);

    gemm_bt<1><<<gg, bb, 0, stream>>>(q, Wq, bq, Qb, B*S, H*DK, D, SCALE);
    gemm_bt<1><<<gg, bb, 0, stream>>>(k, Wk, bk, Kb, B*S, H*DK, D, 1.0f);
    gemm_bt<2><<<gg, bb, 0, stream>>>(v, Wv, bv, Vt, B*S, H*DK, D, 1.0f);

    attn_mfma<<<dim3(B*H*(S/64)), bb, 0, stream>>>(Qb, Kb, Vt, prev, mask, Ao);

    gemm_bt<0><<<gg, bb, 0, stream>>>(Ao, Wo, bo, out, B*S, D, H*DK, 1.0f);
}